// Round 4
// baseline (3918.773 us; speedup 1.0000x reference)
//
#include <hip/hip_runtime.h>
#include <hip/hip_bf16.h>
#include <stdint.h>

#define Bb 32
#define Tt 2048
#define Dd 1024   // D_IN = D_H = D_OUT

typedef float    f32x4 __attribute__((ext_vector_type(4)));
typedef _Float16 f16x8 __attribute__((ext_vector_type(8)));

// ---- ws layout (bytes) ----  total ~6.7 MB  (identical to rounds 2-3)
// 0        w_ws  [32][1024] f32              128K
// 131072   e_ws  [32][2048] f32              256K
// 393216   a_ws  [32][2048] f32              256K
// 655360   cpart [32 tc][32 b][1024] f32     4M
// 4849664  U_t   [1024 o][1024 k] fp16 (U transposed, linear)  2M
#define WS_E     131072
#define WS_A     393216
#define WS_CP    655360
#define WS_UT    4849664

// ---------------- kernel 1: w[b][o] = sum_i s[b][i] * W[i][o] ----------------
__global__ __launch_bounds__(256) void k_ws(const float* __restrict__ s,
                                            const float* __restrict__ W,
                                            float* __restrict__ w_ws) {
  const int b = blockIdx.x >> 2;
  const int o = (blockIdx.x & 3) * 256 + threadIdx.x;
  __shared__ float s_sh[Dd];
#pragma unroll
  for (int j = 0; j < 4; ++j)
    s_sh[threadIdx.x + 256 * j] = s[b * Dd + threadIdx.x + 256 * j];
  __syncthreads();
  float acc = 0.f;
#pragma unroll 8
  for (int i = 0; i < Dd; ++i) acc += s_sh[i] * W[(size_t)i * Dd + o];
  w_ws[b * Dd + o] = acc;
}

// ------- kernel 2: U_t[o][k] = fp16(U[k][o]), plain linear layout -------
__global__ __launch_bounds__(256) void k_ut(const float* __restrict__ U,
                                            _Float16* __restrict__ U_t) {
  const int i0 = (blockIdx.x >> 4) * 64;   // k-dim tile
  const int o0 = (blockIdx.x & 15) * 64;   // o-dim tile
  __shared__ float tile[64][65];
  const int tx = threadIdx.x & 63;
  const int ty = threadIdx.x >> 6;         // 0..3
#pragma unroll
  for (int jj = 0; jj < 16; ++jj)
    tile[tx][ty + 4 * jj] = U[(size_t)(i0 + ty + 4 * jj) * Dd + o0 + tx];  // tile[o_loc][k_loc]
  __syncthreads();
#pragma unroll
  for (int jj = 0; jj < 16; ++jj) {
    const int o = o0 + ty + 4 * jj;
    const int k = i0 + tx;
    U_t[(size_t)o * Dd + k] = (_Float16)tile[ty + 4 * jj][tx];
  }
}

// ---------------- kernel 3 (VALU version): e[b][t] = sum_o v_o * tanh(w + h.U) ----------------
__global__ __launch_bounds__(256) void k_e_valu(const float* __restrict__ h,
                                                const _Float16* __restrict__ U_t,
                                                const float* __restrict__ w_ws,
                                                const float* __restrict__ v_a,
                                                float* __restrict__ e_ws) {
  const int b   = blockIdx.x >> 7;          // 4096 blocks: 32 b x 128 t-chunks
  const int t0  = (blockIdx.x & 127) << 4;  // 16 t per block
  const int tid = threadIdx.x;
  const int tt  = tid >> 7;                 // 0..1  (which 8-t half)
  const int og  = tid & 127;                // o-group: owns o = og*8 .. og*8+7

  __shared__ _Float16 h_sh[16][1024];       // 32KB
  __shared__ float    e_sh[16][128];        // 8KB

  for (int r = 0; r < 16; ++r) {
    const f32x4 hv = *(const f32x4*)(h + ((size_t)b * Tt + t0 + r) * Dd + tid * 4);
    _Float16* dst = &h_sh[r][tid * 4];
    dst[0] = (_Float16)hv[0]; dst[1] = (_Float16)hv[1];
    dst[2] = (_Float16)hv[2]; dst[3] = (_Float16)hv[3];
  }
  __syncthreads();

  float acc[8][8] = {};  // [ti][oi]
  const _Float16* Ub = U_t + (size_t)og * 8 * Dd;
  for (int kb = 0; kb < 128; ++kb) {
    f16x8 u8[8], h8[8];
#pragma unroll
    for (int oi = 0; oi < 8; ++oi) u8[oi] = *(const f16x8*)(Ub + (size_t)oi * Dd + kb * 8);
#pragma unroll
    for (int ti = 0; ti < 8; ++ti) h8[ti] = *(const f16x8*)(&h_sh[tt * 8 + ti][kb * 8]);
#pragma unroll
    for (int ti = 0; ti < 8; ++ti)
#pragma unroll
      for (int oi = 0; oi < 8; ++oi)
#pragma unroll
        for (int j = 0; j < 8; ++j)
          acc[ti][oi] += (float)h8[ti][j] * (float)u8[oi][j];
  }

#pragma unroll
  for (int ti = 0; ti < 8; ++ti) {
    float sv = 0.f;
#pragma unroll
    for (int oi = 0; oi < 8; ++oi) {
      const int o = og * 8 + oi;
      const float x = acc[ti][oi] + w_ws[b * Dd + o];
      sv += v_a[o] * (1.f - 2.f / (__expf(2.f * x) + 1.f));  // tanh, inf-safe
    }
    e_sh[tt * 8 + ti][og] = sv;
  }
  __syncthreads();
  if (tid < 16) {
    float sv = 0.f;
    for (int j = 0; j < 128; ++j) sv += e_sh[tid][j];
    e_ws[b * Tt + t0 + tid] = sv;
  }
}

// ---------------- kernel 4: softmax over T per b ----------------
__global__ __launch_bounds__(256) void k_sm(const float* __restrict__ e_ws,
                                            float* __restrict__ a_ws) {
  const int b = blockIdx.x;
  const int lane = threadIdx.x & 63;
  const int wv = threadIdx.x >> 6;
  __shared__ float red[8];
  float ev[8];
  float m = -1e30f;
#pragma unroll
  for (int j = 0; j < 8; ++j) {
    ev[j] = e_ws[b * Tt + threadIdx.x + 256 * j];
    m = fmaxf(m, ev[j]);
  }
#pragma unroll
  for (int sft = 1; sft < 64; sft <<= 1) m = fmaxf(m, __shfl_xor(m, sft, 64));
  if (lane == 0) red[wv] = m;
  __syncthreads();
  m = fmaxf(fmaxf(red[0], red[1]), fmaxf(red[2], red[3]));
  float sum = 0.f;
#pragma unroll
  for (int j = 0; j < 8; ++j) { ev[j] = __expf(ev[j] - m); sum += ev[j]; }
#pragma unroll
  for (int sft = 1; sft < 64; sft <<= 1) sum += __shfl_xor(sum, sft, 64);
  if (lane == 0) red[4 + wv] = sum;
  __syncthreads();
  const float inv = 1.f / (red[4] + red[5] + red[6] + red[7]);
#pragma unroll
  for (int j = 0; j < 8; ++j) a_ws[b * Tt + threadIdx.x + 256 * j] = ev[j] * inv;
}

// ---------------- kernel 5a: partial c over 64-t chunks (deterministic) ----------------
__global__ __launch_bounds__(256) void k_c1(const float* __restrict__ h,
                                            const float* __restrict__ a_ws,
                                            float* __restrict__ cpart) {
  const int b  = blockIdx.x >> 5;
  const int tc = blockIdx.x & 31;
  const int t0 = tc << 6;
  __shared__ float a_sh[64];
  if (threadIdx.x < 64) a_sh[threadIdx.x] = a_ws[b * Tt + t0 + threadIdx.x];
  __syncthreads();
  f32x4 acc = {0.f, 0.f, 0.f, 0.f};
  const float* hb = h + ((size_t)b * Tt + t0) * Dd + threadIdx.x * 4;
#pragma unroll 4
  for (int t = 0; t < 64; ++t) {
    const f32x4 hv = *(const f32x4*)(hb + (size_t)t * Dd);
    acc += a_sh[t] * hv;
  }
  *(f32x4*)(cpart + ((size_t)(tc * 32 + b) << 10) + threadIdx.x * 4) = acc;
}

// ---------------- kernel 5b: reduce partials, store f32 (per harness docs: ref output dtype) ----------------
__global__ __launch_bounds__(256) void k_c2(const float* __restrict__ cpart,
                                            float* __restrict__ out) {
  const int gid = blockIdx.x * 256 + threadIdx.x;   // 0..32767
  const int b = gid >> 10;
  const int d = gid & 1023;
  float sv = 0.f;
#pragma unroll
  for (int tc = 0; tc < 32; ++tc) sv += cpart[((size_t)(tc * 32 + b) << 10) + d];
  out[gid] = sv;
}

extern "C" void kernel_launch(void* const* d_in, const int* in_sizes, int n_in,
                              void* d_out, int out_size, void* d_ws, size_t ws_size,
                              hipStream_t stream) {
  (void)in_sizes; (void)n_in; (void)out_size; (void)ws_size;
  const float* s  = (const float*)d_in[0];
  const float* h  = (const float*)d_in[1];
  const float* W  = (const float*)d_in[2];
  const float* U  = (const float*)d_in[3];
  const float* v  = (const float*)d_in[4];
  uint8_t* ws = (uint8_t*)d_ws;
  float*     w_ws  = (float*)ws;
  float*     e_ws  = (float*)(ws + WS_E);
  float*     a_ws  = (float*)(ws + WS_A);
  float*     cpart = (float*)(ws + WS_CP);
  _Float16*  U_t   = (_Float16*)(ws + WS_UT);

  k_ws<<<128, 256, 0, stream>>>(s, W, w_ws);
  k_ut<<<256, 256, 0, stream>>>(U, U_t);
  k_e_valu<<<4096, 256, 0, stream>>>(h, U_t, w_ws, v, e_ws);
  k_sm<<<Bb, 256, 0, stream>>>(e_ws, a_ws);
  k_c1<<<1024, 256, 0, stream>>>(h, a_ws, cpart);
  k_c2<<<128, 256, 0, stream>>>(cpart, (float*)d_out);
}

// Round 5
// 309.969 us; speedup vs baseline: 12.6425x; 12.6425x over previous
//
#include <hip/hip_runtime.h>
#include <hip/hip_bf16.h>
#include <stdint.h>

#define Bb 32
#define Tt 2048
#define Dd 1024   // D_IN = D_H = D_OUT

typedef float    f32x4 __attribute__((ext_vector_type(4)));
typedef _Float16 f16x8 __attribute__((ext_vector_type(8)));
typedef uint32_t u32;

// ---- ws layout (bytes) ----
// 0        w_ws  [32][1024] f32              128K
// 131072   e_ws  [32][2048] f32              256K
// 393216   a_ws  [32][2048] f32              256K
// 655360   cpart [32 tc][32 b][1024] f32     4M
// 4849664  U_ts  [1024 o][2048 B] fp16 U^T, XOR-swizzled within 128B  2M
#define WS_E     131072
#define WS_A     393216
#define WS_CP    655360
#define WS_UT    4849664

__device__ __forceinline__ void gll16(const void* g, const void* lds) {
  __builtin_amdgcn_global_load_lds(
      (const __attribute__((address_space(1))) u32*)(uintptr_t)g,
      (__attribute__((address_space(3))) u32*)(uint32_t)(uintptr_t)lds,
      16, 0, 0);
}

// ---------------- kernel 1: w[b][o] = sum_i s[b][i] * W[i][o]  (no atomics) ----------------
__global__ __launch_bounds__(256) void k_ws(const float* __restrict__ s,
                                            const float* __restrict__ W,
                                            float* __restrict__ w_ws) {
  const int b = blockIdx.x >> 2;
  const int o = (blockIdx.x & 3) * 256 + threadIdx.x;
  __shared__ float s_sh[Dd];
#pragma unroll
  for (int j = 0; j < 4; ++j)
    s_sh[threadIdx.x + 256 * j] = s[b * Dd + threadIdx.x + 256 * j];
  __syncthreads();
  float acc = 0.f;
#pragma unroll 8
  for (int i = 0; i < Dd; ++i) acc += s_sh[i] * W[(size_t)i * Dd + o];
  w_ws[b * Dd + o] = acc;
}

// ------- kernel 2: U_ts[o][k] = fp16(U[k][o]), swizzled byte ^= (o&7)<<4 -------
__global__ __launch_bounds__(256) void k_ut(const float* __restrict__ U,
                                            uint8_t* __restrict__ U_ts) {
  const int i0 = (blockIdx.x >> 4) * 64;   // k-dim tile
  const int o0 = (blockIdx.x & 15) * 64;   // o-dim tile
  __shared__ float tile[64][65];
  const int tx = threadIdx.x & 63;
  const int ty = threadIdx.x >> 6;         // 0..3
#pragma unroll
  for (int jj = 0; jj < 16; ++jj)
    tile[tx][ty + 4 * jj] = U[(size_t)(i0 + ty + 4 * jj) * Dd + o0 + tx];  // tile[o_loc][k_loc]
  __syncthreads();
#pragma unroll
  for (int jj = 0; jj < 16; ++jj) {
    const int o_loc = ty + 4 * jj;
    const int o = o0 + o_loc;
    const int k = i0 + tx;
    const _Float16 hv = (_Float16)tile[o_loc][tx];
    const size_t byte = (size_t)o * 2048 + (((u32)k * 2u) ^ (u32)((o & 7) << 4));
    *(uint16_t*)(U_ts + byte) = *(const uint16_t*)&hv;
  }
}

// ---------------- kernel 3: fused  e[b][t] = sum_o v_o * tanh(w + h.U) ----------------
// D[o][t]: A = U^T (M=o,K=i) via global_load_lds from pre-swizzled U_ts, B = h^T in regs.
__global__ __launch_bounds__(256, 2) void k_e(const float* __restrict__ h,
                                              const uint8_t* __restrict__ U_ts,
                                              const float* __restrict__ w_ws,
                                              const float* __restrict__ v_a,
                                              float* __restrict__ e_ws) {
  const int b    = blockIdx.x >> 5;
  const int t0   = (blockIdx.x & 31) << 6;   // 64 t-rows per block
  const int lane = threadIdx.x & 63;
  const int wv   = threadIdx.x >> 6;         // wave 0..3, owns 16 t-rows

  __shared__ __align__(16) uint8_t ubuf[2][32 * 512];  // 2 x [32 o][512 B]
  __shared__ float w_sh[Dd];
  __shared__ float v_sh[Dd];

#pragma unroll
  for (int j = 0; j < 4; ++j) {
    const int o = threadIdx.x + 256 * j;
    w_sh[o] = w_ws[b * Dd + o];
    v_sh[o] = v_a[o];
  }

  // B-operand: this wave's 16 h-rows, fp16, in registers (h read exactly once)
  const int trow = t0 + 16 * wv + (lane & 15);
  const int kcol = (lane >> 4) * 8;
  const float* hbase = h + ((size_t)b * Tt + trow) * Dd + kcol;
  f16x8 hreg[32];
#pragma unroll
  for (int ks = 0; ks < 32; ++ks) {
    const f32x4 p0 = *(const f32x4*)(hbase + ks * 32);
    const f32x4 p1 = *(const f32x4*)(hbase + ks * 32 + 4);
    f16x8 r;
    r[0] = (_Float16)p0[0]; r[1] = (_Float16)p0[1];
    r[2] = (_Float16)p0[2]; r[3] = (_Float16)p0[3];
    r[4] = (_Float16)p1[0]; r[5] = (_Float16)p1[1];
    r[6] = (_Float16)p1[2]; r[7] = (_Float16)p1[3];
    hreg[ks] = r;
  }

  // chunk c (0..127): U_ts rows (c>>2)*32..+31, bytes (c&3)*512 of each 2048B row
  auto stage = [&](int c, int buf) {
    const uint8_t* src = U_ts + (size_t)(c >> 2) * (32 * 2048) + (size_t)(c & 3) * 512;
#pragma unroll
    for (int q = 0; q < 4; ++q) {
      const int r0 = 8 * wv + 2 * q;  // wave-uniform; HW writes base + lane*16
      gll16(src + (size_t)(r0 + (lane >> 5)) * 2048 + (size_t)(lane & 31) * 16,
            &ubuf[buf][r0 * 512]);
    }
  };

  stage(0, 0);
  __syncthreads();

  float epart = 0.f;
  const int ol0 = lane & 15;
  const int ol1 = ol0 + 16;
  const u32 kb  = (u32)((lane >> 4) * 16);
  const u32 sw  = (u32)((ol0 & 7) << 4);

  for (int ot = 0; ot < 32; ++ot) {
    f32x4 acc0 = {0.f, 0.f, 0.f, 0.f};
    f32x4 acc1 = {0.f, 0.f, 0.f, 0.f};
#pragma unroll
    for (int kc = 0; kc < 4; ++kc) {
      const int c   = ot * 4 + kc;
      const int cur = kc & 1;            // == c & 1
      if (c + 1 < 128) stage(c + 1, cur ^ 1);   // prev-phase barrier cleared cur^1 readers
      const uint8_t* ub = &ubuf[cur][0];
#pragma unroll
      for (int kk = 0; kk < 8; ++kk) {
        const u32 kbyte = (u32)(kk * 64) + kb;
        const f16x8 a0 = *(const f16x8*)(ub + ol0 * 512 + (kbyte ^ sw));
        const f16x8 a1 = *(const f16x8*)(ub + ol1 * 512 + (kbyte ^ sw));
        acc0 = __builtin_amdgcn_mfma_f32_16x16x32_f16(a0, hreg[kc * 8 + kk], acc0, 0, 0, 0);
        acc1 = __builtin_amdgcn_mfma_f32_16x16x32_f16(a1, hreg[kc * 8 + kk], acc1, 0, 0, 0);
      }
      __syncthreads();   // drains vmcnt (gll16) + orders LDS reads vs next stage
    }
    // lane holds D rows o_loc = 4*(lane>>4)+r (acc0), +16 (acc1); col t_loc = lane&15
    const int ob = (ot << 5) + ((lane >> 4) << 2);
#pragma unroll
    for (int r = 0; r < 4; ++r) {
      const float x0 = acc0[r] + w_sh[ob + r];
      const float x1 = acc1[r] + w_sh[ob + 16 + r];
      epart += v_sh[ob + r]      * (1.f - 2.f / (__expf(2.f * x0) + 1.f));
      epart += v_sh[ob + 16 + r] * (1.f - 2.f / (__expf(2.f * x1) + 1.f));
    }
  }
  epart += __shfl_xor(epart, 16, 64);
  epart += __shfl_xor(epart, 32, 64);
  if (lane < 16) e_ws[b * Tt + t0 + 16 * wv + lane] = epart;
}

// ---------------- kernel 4: softmax over T per b ----------------
__global__ __launch_bounds__(256) void k_sm(const float* __restrict__ e_ws,
                                            float* __restrict__ a_ws) {
  const int b = blockIdx.x;
  const int lane = threadIdx.x & 63;
  const int wv = threadIdx.x >> 6;
  __shared__ float red[8];
  float ev[8];
  float m = -1e30f;
#pragma unroll
  for (int j = 0; j < 8; ++j) {
    ev[j] = e_ws[b * Tt + threadIdx.x + 256 * j];
    m = fmaxf(m, ev[j]);
  }
#pragma unroll
  for (int sft = 1; sft < 64; sft <<= 1) m = fmaxf(m, __shfl_xor(m, sft, 64));
  if (lane == 0) red[wv] = m;
  __syncthreads();
  m = fmaxf(fmaxf(red[0], red[1]), fmaxf(red[2], red[3]));
  float sum = 0.f;
#pragma unroll
  for (int j = 0; j < 8; ++j) { ev[j] = __expf(ev[j] - m); sum += ev[j]; }
#pragma unroll
  for (int sft = 1; sft < 64; sft <<= 1) sum += __shfl_xor(sum, sft, 64);
  if (lane == 0) red[4 + wv] = sum;
  __syncthreads();
  const float inv = 1.f / (red[4] + red[5] + red[6] + red[7]);
#pragma unroll
  for (int j = 0; j < 8; ++j) a_ws[b * Tt + threadIdx.x + 256 * j] = ev[j] * inv;
}

// ---------------- kernel 5a: partial c over 64-t chunks (deterministic) ----------------
__global__ __launch_bounds__(256) void k_c1(const float* __restrict__ h,
                                            const float* __restrict__ a_ws,
                                            float* __restrict__ cpart) {
  const int b  = blockIdx.x >> 5;
  const int tc = blockIdx.x & 31;
  const int t0 = tc << 6;
  __shared__ float a_sh[64];
  if (threadIdx.x < 64) a_sh[threadIdx.x] = a_ws[b * Tt + t0 + threadIdx.x];
  __syncthreads();
  f32x4 acc = {0.f, 0.f, 0.f, 0.f};
  const float* hb = h + ((size_t)b * Tt + t0) * Dd + threadIdx.x * 4;
#pragma unroll 4
  for (int t = 0; t < 64; ++t) {
    const f32x4 hv = *(const f32x4*)(hb + (size_t)t * Dd);
    acc += a_sh[t] * hv;
  }
  *(f32x4*)(cpart + ((size_t)(tc * 32 + b) << 10) + threadIdx.x * 4) = acc;
}

// ---------------- kernel 5b: reduce partials, store f32 ----------------
__global__ __launch_bounds__(256) void k_c2(const float* __restrict__ cpart,
                                            float* __restrict__ out) {
  const int gid = blockIdx.x * 256 + threadIdx.x;   // 0..32767
  const int b = gid >> 10;
  const int d = gid & 1023;
  float sv = 0.f;
#pragma unroll
  for (int tc = 0; tc < 32; ++tc) sv += cpart[((size_t)(tc * 32 + b) << 10) + d];
  out[gid] = sv;
}

extern "C" void kernel_launch(void* const* d_in, const int* in_sizes, int n_in,
                              void* d_out, int out_size, void* d_ws, size_t ws_size,
                              hipStream_t stream) {
  (void)in_sizes; (void)n_in; (void)out_size; (void)ws_size;
  const float* s  = (const float*)d_in[0];
  const float* h  = (const float*)d_in[1];
  const float* W  = (const float*)d_in[2];
  const float* U  = (const float*)d_in[3];
  const float* v  = (const float*)d_in[4];
  uint8_t* ws = (uint8_t*)d_ws;
  float*   w_ws  = (float*)ws;
  float*   e_ws  = (float*)(ws + WS_E);
  float*   a_ws  = (float*)(ws + WS_A);
  float*   cpart = (float*)(ws + WS_CP);
  uint8_t* U_ts  = ws + WS_UT;

  k_ws<<<128, 256, 0, stream>>>(s, W, w_ws);
  k_ut<<<256, 256, 0, stream>>>(U, U_ts);
  k_e <<<1024, 256, 0, stream>>>(h, U_ts, w_ws, v, e_ws);
  k_sm<<<Bb, 256, 0, stream>>>(e_ws, a_ws);
  k_c1<<<1024, 256, 0, stream>>>(h, a_ws, cpart);
  k_c2<<<128, 256, 0, stream>>>(cpart, (float*)d_out);
}

// Round 6
// 306.814 us; speedup vs baseline: 12.7725x; 1.0103x over previous
//
#include <hip/hip_runtime.h>
#include <hip/hip_bf16.h>
#include <stdint.h>

#define Bb 32
#define Tt 2048
#define Dd 1024   // D_IN = D_H = D_OUT

typedef float    f32x4 __attribute__((ext_vector_type(4)));
typedef _Float16 f16x8 __attribute__((ext_vector_type(8)));
typedef uint32_t u32;

// ---- ws layout (bytes) ----
// 0        w2_ws [32][1024] f32  (2 * s.W_a)     128K
// 131072   e_ws  [32][2048] f32                  256K
// 393216   a_ws  [32][2048] f32                  256K
// 655360   cpart [32 tc][32 b][1024] f32         4M
// 4849664  U_ts  chunk-major fp16 U^T:           2M
//          chunk c (o-block c>>2, k-window (c&3)*256) = 16KB laid out as
//          [kk 0..7][o-half 0..1][lane 0..63][16B]:
//          element (o,k): c=(o>>5)*4+(k>>8); kk=(k>>5)&7; half=(o>>4)&1;
//          lane=((k>>3)&3)*16+(o&15); m=k&7.
#define WS_E     131072
#define WS_A     393216
#define WS_CP    655360
#define WS_UT    4849664

__device__ __forceinline__ void gll16(const void* g, const void* lds) {
  __builtin_amdgcn_global_load_lds(
      (const __attribute__((address_space(1))) u32*)(uintptr_t)g,
      (__attribute__((address_space(3))) u32*)(uint32_t)(uintptr_t)lds,
      16, 0, 0);
}

// ---------------- kernel 1: w2[b][o] = 2 * sum_i s[b][i] * W[i][o] ----------------
__global__ __launch_bounds__(256) void k_ws(const float* __restrict__ s,
                                            const float* __restrict__ W,
                                            float* __restrict__ w2_ws) {
  const int b = blockIdx.x >> 2;
  const int o = (blockIdx.x & 3) * 256 + threadIdx.x;
  __shared__ float s_sh[Dd];
#pragma unroll
  for (int j = 0; j < 4; ++j)
    s_sh[threadIdx.x + 256 * j] = s[b * Dd + threadIdx.x + 256 * j];
  __syncthreads();
  float acc = 0.f;
#pragma unroll 8
  for (int i = 0; i < Dd; ++i) acc += s_sh[i] * W[(size_t)i * Dd + o];
  w2_ws[b * Dd + o] = 2.f * acc;
}

// ------- kernel 2: build U_ts in linear-lane chunk layout -------
__global__ __launch_bounds__(256) void k_ut(const float* __restrict__ U,
                                            uint8_t* __restrict__ U_ts) {
  const int i0 = (blockIdx.x >> 4) * 64;   // k-tile
  const int o0 = (blockIdx.x & 15) * 64;   // o-tile
  __shared__ float tile[64][65];           // [o_loc][k_loc]
  const int tx = threadIdx.x & 63;
  const int ty = threadIdx.x >> 6;
#pragma unroll
  for (int jj = 0; jj < 16; ++jj)
    tile[tx][ty + 4 * jj] = U[(size_t)(i0 + ty + 4 * jj) * Dd + o0 + tx];
  __syncthreads();
#pragma unroll
  for (int it = 0; it < 2; ++it) {
    const int g = it * 256 + threadIdx.x;  // 0..511
    const int o_loc = g & 63;
    const int kg = g >> 6;                 // 0..7
    const int o = o0 + o_loc;
    const int k = i0 + kg * 8;
    f16x8 r;
#pragma unroll
    for (int m = 0; m < 8; ++m) r[m] = (_Float16)tile[o_loc][kg * 8 + m];
    const int c    = (o >> 5) * 4 + (k >> 8);
    const int kk   = (k >> 5) & 7;
    const int half = (o >> 4) & 1;
    const int ln   = ((k >> 3) & 3) * 16 + (o & 15);
    *(f16x8*)(U_ts + (size_t)c * 16384 + kk * 2048 + half * 1024 + ln * 16) = r;
  }
}

// ---------------- kernel 3: fused  e[b][t] = sum_o v_o * tanh(w + h.U) ----------------
// Waves: bit0 = K-half (kh), bit1 = t-half (th). Each wave: 32o x 32t tile per ot
// phase over its K-half; partial accs exchanged through LDS before tanh.
__global__ __launch_bounds__(256, 2) void k_e(const float* __restrict__ h,
                                              const uint8_t* __restrict__ U_ts,
                                              const float* __restrict__ w2_ws,
                                              const float* __restrict__ v_a,
                                              float* __restrict__ e_ws) {
  const int b    = blockIdx.x >> 5;
  const int t0   = (blockIdx.x & 31) << 6;   // 64 t per block
  const int lane = threadIdx.x & 63;
  const int wv   = threadIdx.x >> 6;
  const int kh   = wv & 1;                   // K-half
  const int th   = wv >> 1;                  // t-half

  __shared__ __align__(16) uint8_t ubuf[2][16384];  // chunk double-buffer
  __shared__ __align__(16) float   exch[2048];      // 4 waves x 2 tiles x 256 f32

  // B-operand: 32 t-cols (2 MFMA col-tiles), this wave's K-half of each 256-window.
  // hreg[(kc*4+kkl)*2 + tc]; k = kc*256 + kh*128 + kkl*32 + (lane>>4)*8 + j
  f16x8 hreg[32];
  {
    const int tcol = t0 + th * 32 + (lane & 15);
    const int kgrp = (lane >> 4) * 8;
    const float* hb0 = h + ((size_t)b * Tt + tcol) * Dd;
    const float* hb1 = hb0 + (size_t)16 * Dd;
#pragma unroll
    for (int ss = 0; ss < 16; ++ss) {
      const int kbase = (ss >> 2) * 256 + kh * 128 + (ss & 3) * 32 + kgrp;
      f32x4 p0 = *(const f32x4*)(hb0 + kbase);
      f32x4 p1 = *(const f32x4*)(hb0 + kbase + 4);
      f16x8 r;
      r[0] = (_Float16)p0[0]; r[1] = (_Float16)p0[1];
      r[2] = (_Float16)p0[2]; r[3] = (_Float16)p0[3];
      r[4] = (_Float16)p1[0]; r[5] = (_Float16)p1[1];
      r[6] = (_Float16)p1[2]; r[7] = (_Float16)p1[3];
      hreg[ss * 2] = r;
      p0 = *(const f32x4*)(hb1 + kbase);
      p1 = *(const f32x4*)(hb1 + kbase + 4);
      r[0] = (_Float16)p0[0]; r[1] = (_Float16)p0[1];
      r[2] = (_Float16)p0[2]; r[3] = (_Float16)p0[3];
      r[4] = (_Float16)p1[0]; r[5] = (_Float16)p1[1];
      r[6] = (_Float16)p1[2]; r[7] = (_Float16)p1[3];
      hreg[ss * 2 + 1] = r;
    }
  }

  // stage chunk c: 16 linear 1KB segments, 4 gll16 per wave
  auto stage = [&](int c, int buf) {
    const uint8_t* src = U_ts + (size_t)c * 16384 + (size_t)(wv * 4) * 1024 + (size_t)lane * 16;
#pragma unroll
    for (int q = 0; q < 4; ++q)
      gll16(src + q * 1024, &ubuf[buf][(wv * 4 + q) * 1024]);
  };

  stage(0, 0);
  __syncthreads();

  float ep0 = 0.f, ep1 = 0.f;
  const float* wp  = w2_ws + b * Dd;
  const int    obl = kh * 16 + ((lane >> 4) << 2);

  for (int ot = 0; ot < 32; ++ot) {
    const f32x4 w4 = *(const f32x4*)(wp + (ot << 5) + obl);   // drained by kc0 barrier
    const f32x4 v4 = *(const f32x4*)(v_a + (ot << 5) + obl);
    f32x4 accA0 = {0.f,0.f,0.f,0.f}, accA1 = {0.f,0.f,0.f,0.f};  // o-half 0, tc 0/1
    f32x4 accB0 = {0.f,0.f,0.f,0.f}, accB1 = {0.f,0.f,0.f,0.f};  // o-half 1, tc 0/1
#pragma unroll
    for (int kc = 0; kc < 4; ++kc) {
      const int c   = ot * 4 + kc;
      const int cur = kc & 1;
      if (c + 1 < 128) stage(c + 1, cur ^ 1);
      const uint8_t* ub = &ubuf[cur][0] + kh * 8192 + lane * 16;  // linear reads
#pragma unroll
      for (int kkl = 0; kkl < 4; ++kkl) {
        const f16x8 a0 = *(const f16x8*)(ub + kkl * 2048);          // o-half 0
        const f16x8 a1 = *(const f16x8*)(ub + kkl * 2048 + 1024);   // o-half 1
        const f16x8 b0 = hreg[(kc * 4 + kkl) * 2];
        const f16x8 b1 = hreg[(kc * 4 + kkl) * 2 + 1];
        accA0 = __builtin_amdgcn_mfma_f32_16x16x32_f16(a0, b0, accA0, 0, 0, 0);
        accA1 = __builtin_amdgcn_mfma_f32_16x16x32_f16(a0, b1, accA1, 0, 0, 0);
        accB0 = __builtin_amdgcn_mfma_f32_16x16x32_f16(a1, b0, accB0, 0, 0, 0);
        accB1 = __builtin_amdgcn_mfma_f32_16x16x32_f16(a1, b1, accB1, 0, 0, 0);
      }
      __syncthreads();
    }
    // exchange partial accs with K-half partner (wv^1); keep o-half == kh
    {
      float* snd = exch + wv * 512 + lane * 4;   // linear b128 writes
      if (kh == 0) { *(f32x4*)snd = accB0; *(f32x4*)(snd + 256) = accB1; }
      else         { *(f32x4*)snd = accA0; *(f32x4*)(snd + 256) = accA1; }
    }
    __syncthreads();
    {
      const float* rcv = exch + (wv ^ 1) * 512 + lane * 4;
      const f32x4 q0 = *(const f32x4*)rcv;
      const f32x4 q1 = *(const f32x4*)(rcv + 256);
      f32x4 x0, x1;
      if (kh == 0) { x0 = accA0 + q0; x1 = accA1 + q1; }
      else         { x0 = accB0 + q0; x1 = accB1 + q1; }
#pragma unroll
      for (int r = 0; r < 4; ++r) {
        const float e0 = __expf(__builtin_fmaf(x0[r], 2.f, w4[r]));  // exp(2(acc+w))
        const float e1 = __expf(__builtin_fmaf(x1[r], 2.f, w4[r]));
        ep0 += v4[r] * (1.f - 2.f / (e0 + 1.f));
        ep1 += v4[r] * (1.f - 2.f / (e1 + 1.f));
      }
    }
    // next ot's first stage/write is gated by its kc barriers -> no extra barrier
  }

  // reduce over row-groups (o within wave), then over K-half pair via LDS
  ep0 += __shfl_xor(ep0, 16, 64); ep0 += __shfl_xor(ep0, 32, 64);
  ep1 += __shfl_xor(ep1, 16, 64); ep1 += __shfl_xor(ep1, 32, 64);
  __syncthreads();   // all exchange reads done before exch reuse
  if (kh == 1 && lane < 16) {
    exch[th * 32 + lane]      = ep0;
    exch[th * 32 + 16 + lane] = ep1;
  }
  __syncthreads();
  if (kh == 0 && lane < 16) {
    e_ws[b * Tt + t0 + th * 32 + lane]      = ep0 + exch[th * 32 + lane];
    e_ws[b * Tt + t0 + th * 32 + 16 + lane] = ep1 + exch[th * 32 + 16 + lane];
  }
}

// ---------------- kernel 4: softmax over T per b ----------------
__global__ __launch_bounds__(256) void k_sm(const float* __restrict__ e_ws,
                                            float* __restrict__ a_ws) {
  const int b = blockIdx.x;
  const int lane = threadIdx.x & 63;
  const int wv = threadIdx.x >> 6;
  __shared__ float red[8];
  float ev[8];
  float m = -1e30f;
#pragma unroll
  for (int j = 0; j < 8; ++j) {
    ev[j] = e_ws[b * Tt + threadIdx.x + 256 * j];
    m = fmaxf(m, ev[j]);
  }
#pragma unroll
  for (int sft = 1; sft < 64; sft <<= 1) m = fmaxf(m, __shfl_xor(m, sft, 64));
  if (lane == 0) red[wv] = m;
  __syncthreads();
  m = fmaxf(fmaxf(red[0], red[1]), fmaxf(red[2], red[3]));
  float sum = 0.f;
#pragma unroll
  for (int j = 0; j < 8; ++j) { ev[j] = __expf(ev[j] - m); sum += ev[j]; }
#pragma unroll
  for (int sft = 1; sft < 64; sft <<= 1) sum += __shfl_xor(sum, sft, 64);
  if (lane == 0) red[4 + wv] = sum;
  __syncthreads();
  const float inv = 1.f / (red[4] + red[5] + red[6] + red[7]);
#pragma unroll
  for (int j = 0; j < 8; ++j) a_ws[b * Tt + threadIdx.x + 256 * j] = ev[j] * inv;
}

// ---------------- kernel 5a: partial c over 64-t chunks (deterministic) ----------------
__global__ __launch_bounds__(256) void k_c1(const float* __restrict__ h,
                                            const float* __restrict__ a_ws,
                                            float* __restrict__ cpart) {
  const int b  = blockIdx.x >> 5;
  const int tc = blockIdx.x & 31;
  const int t0 = tc << 6;
  __shared__ float a_sh[64];
  if (threadIdx.x < 64) a_sh[threadIdx.x] = a_ws[b * Tt + t0 + threadIdx.x];
  __syncthreads();
  f32x4 acc = {0.f, 0.f, 0.f, 0.f};
  const float* hb = h + ((size_t)b * Tt + t0) * Dd + threadIdx.x * 4;
#pragma unroll 4
  for (int t = 0; t < 64; ++t) {
    const f32x4 hv = *(const f32x4*)(hb + (size_t)t * Dd);
    acc += a_sh[t] * hv;
  }
  *(f32x4*)(cpart + ((size_t)(tc * 32 + b) << 10) + threadIdx.x * 4) = acc;
}

// ---------------- kernel 5b: reduce partials, store f32 ----------------
__global__ __launch_bounds__(256) void k_c2(const float* __restrict__ cpart,
                                            float* __restrict__ out) {
  const int gid = blockIdx.x * 256 + threadIdx.x;   // 0..32767
  const int b = gid >> 10;
  const int d = gid & 1023;
  float sv = 0.f;
#pragma unroll
  for (int tc = 0; tc < 32; ++tc) sv += cpart[((size_t)(tc * 32 + b) << 10) + d];
  out[gid] = sv;
}

extern "C" void kernel_launch(void* const* d_in, const int* in_sizes, int n_in,
                              void* d_out, int out_size, void* d_ws, size_t ws_size,
                              hipStream_t stream) {
  (void)in_sizes; (void)n_in; (void)out_size; (void)ws_size;
  const float* s  = (const float*)d_in[0];
  const float* h  = (const float*)d_in[1];
  const float* W  = (const float*)d_in[2];
  const float* U  = (const float*)d_in[3];
  const float* v  = (const float*)d_in[4];
  uint8_t* ws = (uint8_t*)d_ws;
  float*   w2_ws = (float*)ws;
  float*   e_ws  = (float*)(ws + WS_E);
  float*   a_ws  = (float*)(ws + WS_A);
  float*   cpart = (float*)(ws + WS_CP);
  uint8_t* U_ts  = ws + WS_UT;

  k_ws<<<128, 256, 0, stream>>>(s, W, w2_ws);
  k_ut<<<256, 256, 0, stream>>>(U, U_ts);
  k_e <<<1024, 256, 0, stream>>>(h, U_ts, w2_ws, v, e_ws);
  k_sm<<<Bb, 256, 0, stream>>>(e_ws, a_ws);
  k_c1<<<1024, 256, 0, stream>>>(h, a_ws, cpart);
  k_c2<<<128, 256, 0, stream>>>(cpart, (float*)d_out);
}

// Round 7
// 301.203 us; speedup vs baseline: 13.0104x; 1.0186x over previous
//
#include <hip/hip_runtime.h>
#include <hip/hip_bf16.h>
#include <stdint.h>

#define Bb 32
#define Tt 2048
#define Dd 1024   // D_IN = D_H = D_OUT

typedef float    f32x4 __attribute__((ext_vector_type(4)));
typedef _Float16 f16x8 __attribute__((ext_vector_type(8)));
typedef uint32_t u32;

// ---- ws layout (bytes) ----
// 0        w2_ws [32][1024] f32  (2 * s.W_a)     128K
// 131072   e_ws  [32][2048] f32                  256K
// 393216   a_ws  [32][2048] f32                  256K
// 655360   cpart [32 tc][32 b][1024] f32         4M
// 4849664  U_ts  chunk-major fp16 U^T (linear-lane chunks, see k_ut)  2M
#define WS_E     131072
#define WS_A     393216
#define WS_CP    655360
#define WS_UT    4849664

__device__ __forceinline__ void gll16(const void* g, const void* lds) {
  __builtin_amdgcn_global_load_lds(
      (const __attribute__((address_space(1))) u32*)(uintptr_t)g,
      (__attribute__((address_space(3))) u32*)(uint32_t)(uintptr_t)lds,
      16, 0, 0);
}

// ---------------- kernel 1: w2[b][o] = 2 * sum_i s[b][i] * W[i][o] ----------------
__global__ __launch_bounds__(256) void k_ws(const float* __restrict__ s,
                                            const float* __restrict__ W,
                                            float* __restrict__ w2_ws) {
  const int b = blockIdx.x >> 2;
  const int o = (blockIdx.x & 3) * 256 + threadIdx.x;
  __shared__ float s_sh[Dd];
#pragma unroll
  for (int j = 0; j < 4; ++j)
    s_sh[threadIdx.x + 256 * j] = s[b * Dd + threadIdx.x + 256 * j];
  __syncthreads();
  float acc = 0.f;
#pragma unroll 8
  for (int i = 0; i < Dd; ++i) acc += s_sh[i] * W[(size_t)i * Dd + o];
  w2_ws[b * Dd + o] = 2.f * acc;
}

// ------- kernel 2: build U_ts in linear-lane chunk layout -------
// chunk c (o-block c>>2, k-window (c&3)*256) = 16KB as [kk][o-half][lane][16B]:
// element (o,k): c=(o>>5)*4+(k>>8); kk=(k>>5)&7; half=(o>>4)&1; lane=((k>>3)&3)*16+(o&15).
__global__ __launch_bounds__(256) void k_ut(const float* __restrict__ U,
                                            uint8_t* __restrict__ U_ts) {
  const int i0 = (blockIdx.x >> 4) * 64;   // k-tile
  const int o0 = (blockIdx.x & 15) * 64;   // o-tile
  __shared__ float tile[64][65];           // [o_loc][k_loc]
  const int tx = threadIdx.x & 63;
  const int ty = threadIdx.x >> 6;
#pragma unroll
  for (int jj = 0; jj < 16; ++jj)
    tile[tx][ty + 4 * jj] = U[(size_t)(i0 + ty + 4 * jj) * Dd + o0 + tx];
  __syncthreads();
#pragma unroll
  for (int it = 0; it < 2; ++it) {
    const int g = it * 256 + threadIdx.x;  // 0..511
    const int o_loc = g & 63;
    const int kg = g >> 6;                 // 0..7
    const int o = o0 + o_loc;
    const int k = i0 + kg * 8;
    f16x8 r;
#pragma unroll
    for (int m = 0; m < 8; ++m) r[m] = (_Float16)tile[o_loc][kg * 8 + m];
    const int c    = (o >> 5) * 4 + (k >> 8);
    const int kk   = (k >> 5) & 7;
    const int half = (o >> 4) & 1;
    const int ln   = ((k >> 3) & 3) * 16 + (o & 15);
    *(f16x8*)(U_ts + (size_t)c * 16384 + kk * 2048 + half * 1024 + ln * 16) = r;
  }
}

// ---------------- kernel 3: fused  e[b][t] = sum_o v_o * tanh(w + h.U) ----------------
// Waves: bit0 = K-half (kh), bit1 = t-half (th). Triple-buffered chunks, counted
// vmcnt (never drain to 0 in-loop), ONE raw s_barrier per phase.
__global__ __launch_bounds__(256, 2) void k_e(const float* __restrict__ h,
                                              const uint8_t* __restrict__ U_ts,
                                              const float* __restrict__ w2_ws,
                                              const float* __restrict__ v_a,
                                              float* __restrict__ e_ws) {
  const int b    = blockIdx.x >> 5;
  const int t0   = (blockIdx.x & 31) << 6;   // 64 t per block
  const int lane = threadIdx.x & 63;
  const int wv   = threadIdx.x >> 6;
  const int kh   = wv & 1;                   // K-half
  const int th   = wv >> 1;                  // t-half

  __shared__ __align__(16) uint8_t ubuf[3][16384];  // chunk triple-buffer
  __shared__ __align__(16) float   exch[2048];
  __shared__ float w_sh[Dd];
  __shared__ float v_sh[Dd];

#pragma unroll
  for (int j = 0; j < 4; ++j) {
    const int o = threadIdx.x + 256 * j;
    w_sh[o] = w2_ws[b * Dd + o];
    v_sh[o] = v_a[o];
  }

  // B-operand: 32 t-cols, this wave's K-half of each 256-window, in registers.
  // hreg[(kc*4+kkl)*2 + tc]; k = kc*256 + kh*128 + kkl*32 + (lane>>4)*8 + j
  f16x8 hreg[32];
  {
    const int tcol = t0 + th * 32 + (lane & 15);
    const int kgrp = (lane >> 4) * 8;
    const float* hb0 = h + ((size_t)b * Tt + tcol) * Dd;
    const float* hb1 = hb0 + (size_t)16 * Dd;
#pragma unroll
    for (int ss = 0; ss < 16; ++ss) {
      const int kbase = (ss >> 2) * 256 + kh * 128 + (ss & 3) * 32 + kgrp;
      f32x4 p0 = *(const f32x4*)(hb0 + kbase);
      f32x4 p1 = *(const f32x4*)(hb0 + kbase + 4);
      f16x8 r;
      r[0] = (_Float16)p0[0]; r[1] = (_Float16)p0[1];
      r[2] = (_Float16)p0[2]; r[3] = (_Float16)p0[3];
      r[4] = (_Float16)p1[0]; r[5] = (_Float16)p1[1];
      r[6] = (_Float16)p1[2]; r[7] = (_Float16)p1[3];
      hreg[ss * 2] = r;
      p0 = *(const f32x4*)(hb1 + kbase);
      p1 = *(const f32x4*)(hb1 + kbase + 4);
      r[0] = (_Float16)p0[0]; r[1] = (_Float16)p0[1];
      r[2] = (_Float16)p0[2]; r[3] = (_Float16)p0[3];
      r[4] = (_Float16)p1[0]; r[5] = (_Float16)p1[1];
      r[6] = (_Float16)p1[2]; r[7] = (_Float16)p1[3];
      hreg[ss * 2 + 1] = r;
    }
  }

  // drain prologue (hreg global loads + w/v ds_writes) so vmcnt counting is exact
  asm volatile("s_waitcnt vmcnt(0) lgkmcnt(0)" ::: "memory");

  auto stage = [&](int c, int buf) {
    const uint8_t* src = U_ts + (size_t)c * 16384 + (size_t)(wv * 4) * 1024 + (size_t)lane * 16;
#pragma unroll
    for (int q = 0; q < 4; ++q)
      gll16(src + q * 1024, &ubuf[buf][(wv * 4 + q) * 1024]);
  };

  stage(0, 0);
  stage(1, 1);   // 8 gll16 in flight

  float ep0 = 0.f, ep1 = 0.f;
  const int obl = kh * 16 + ((lane >> 4) << 2);
  int cur = 0;   // buffer holding chunk c

  for (int ot = 0; ot < 32; ++ot) {
    f32x4 accA0 = {0.f,0.f,0.f,0.f}, accA1 = {0.f,0.f,0.f,0.f};  // o-half 0, tc 0/1
    f32x4 accB0 = {0.f,0.f,0.f,0.f}, accB1 = {0.f,0.f,0.f,0.f};  // o-half 1, tc 0/1
#pragma unroll
    for (int kc = 0; kc < 4; ++kc) {
      const int c = ot * 4 + kc;
      // chunk c resident once the 4 newest (chunk c+1) are the only outstanding
      asm volatile("s_waitcnt vmcnt(4)" ::: "memory");
      __builtin_amdgcn_sched_barrier(0);
      __builtin_amdgcn_s_barrier();
      __builtin_amdgcn_sched_barrier(0);
      // prefetch chunk c+2 (wrapped; tail stages are write-only, keep vmcnt uniform)
      const int nxt = cur >= 1 ? cur - 1 : cur + 2;   // (cur+2)%3
      stage((c + 2) & 127, nxt);
      const uint8_t* ub = &ubuf[cur][0] + kh * 8192 + lane * 16;  // linear reads
      __builtin_amdgcn_s_setprio(1);
#pragma unroll
      for (int kkl = 0; kkl < 4; ++kkl) {
        const f16x8 a0 = *(const f16x8*)(ub + kkl * 2048);          // o-half 0
        const f16x8 a1 = *(const f16x8*)(ub + kkl * 2048 + 1024);   // o-half 1
        const f16x8 b0 = hreg[(kc * 4 + kkl) * 2];
        const f16x8 b1 = hreg[(kc * 4 + kkl) * 2 + 1];
        accA0 = __builtin_amdgcn_mfma_f32_16x16x32_f16(a0, b0, accA0, 0, 0, 0);
        accA1 = __builtin_amdgcn_mfma_f32_16x16x32_f16(a0, b1, accA1, 0, 0, 0);
        accB0 = __builtin_amdgcn_mfma_f32_16x16x32_f16(a1, b0, accB0, 0, 0, 0);
        accB1 = __builtin_amdgcn_mfma_f32_16x16x32_f16(a1, b1, accB1, 0, 0, 0);
      }
      __builtin_amdgcn_s_setprio(0);
      cur = cur == 2 ? 0 : cur + 1;
    }
    // exchange partial accs with K-half partner (wv^1); keep o-half == kh
    {
      float* snd = exch + wv * 512 + lane * 4;   // linear b128 writes
      if (kh == 0) { *(f32x4*)snd = accB0; *(f32x4*)(snd + 256) = accB1; }
      else         { *(f32x4*)snd = accA0; *(f32x4*)(snd + 256) = accA1; }
    }
    asm volatile("s_waitcnt lgkmcnt(0)" ::: "memory");  // ds_write retired (NOT vmcnt!)
    __builtin_amdgcn_sched_barrier(0);
    __builtin_amdgcn_s_barrier();
    __builtin_amdgcn_sched_barrier(0);
    {
      const float* rcv = exch + (wv ^ 1) * 512 + lane * 4;
      const f32x4 q0 = *(const f32x4*)rcv;
      const f32x4 q1 = *(const f32x4*)(rcv + 256);
      f32x4 x0, x1;
      if (kh == 0) { x0 = accA0 + q0; x1 = accA1 + q1; }
      else         { x0 = accB0 + q0; x1 = accB1 + q1; }
      const int ob = (ot << 5) + obl;
#pragma unroll
      for (int r = 0; r < 4; ++r) {
        const float wr = w_sh[ob + r];
        const float vr = v_sh[ob + r];
        const float e0 = __expf(__builtin_fmaf(x0[r], 2.f, wr));  // exp(2*acc + 2*w)
        const float e1 = __expf(__builtin_fmaf(x1[r], 2.f, wr));
        ep0 += vr * (1.f - 2.f / (e0 + 1.f));
        ep1 += vr * (1.f - 2.f / (e1 + 1.f));
      }
    }
    // exch reuse is ≥4 barriers away; next phase's barrier orders the read
  }

  // reduce over o row-groups, then over K-half pair via LDS
  ep0 += __shfl_xor(ep0, 16, 64); ep0 += __shfl_xor(ep0, 32, 64);
  ep1 += __shfl_xor(ep1, 16, 64); ep1 += __shfl_xor(ep1, 32, 64);
  __syncthreads();
  if (kh == 1 && lane < 16) {
    exch[th * 32 + lane]      = ep0;
    exch[th * 32 + 16 + lane] = ep1;
  }
  __syncthreads();
  if (kh == 0 && lane < 16) {
    e_ws[b * Tt + t0 + th * 32 + lane]      = ep0 + exch[th * 32 + lane];
    e_ws[b * Tt + t0 + th * 32 + 16 + lane] = ep1 + exch[th * 32 + 16 + lane];
  }
}

// ---------------- kernel 4: softmax over T per b ----------------
__global__ __launch_bounds__(256) void k_sm(const float* __restrict__ e_ws,
                                            float* __restrict__ a_ws) {
  const int b = blockIdx.x;
  const int lane = threadIdx.x & 63;
  const int wv = threadIdx.x >> 6;
  __shared__ float red[8];
  float ev[8];
  float m = -1e30f;
#pragma unroll
  for (int j = 0; j < 8; ++j) {
    ev[j] = e_ws[b * Tt + threadIdx.x + 256 * j];
    m = fmaxf(m, ev[j]);
  }
#pragma unroll
  for (int sft = 1; sft < 64; sft <<= 1) m = fmaxf(m, __shfl_xor(m, sft, 64));
  if (lane == 0) red[wv] = m;
  __syncthreads();
  m = fmaxf(fmaxf(red[0], red[1]), fmaxf(red[2], red[3]));
  float sum = 0.f;
#pragma unroll
  for (int j = 0; j < 8; ++j) { ev[j] = __expf(ev[j] - m); sum += ev[j]; }
#pragma unroll
  for (int sft = 1; sft < 64; sft <<= 1) sum += __shfl_xor(sum, sft, 64);
  if (lane == 0) red[4 + wv] = sum;
  __syncthreads();
  const float inv = 1.f / (red[4] + red[5] + red[6] + red[7]);
#pragma unroll
  for (int j = 0; j < 8; ++j) a_ws[b * Tt + threadIdx.x + 256 * j] = ev[j] * inv;
}

// ---------------- kernel 5a: partial c over 64-t chunks (deterministic) ----------------
__global__ __launch_bounds__(256) void k_c1(const float* __restrict__ h,
                                            const float* __restrict__ a_ws,
                                            float* __restrict__ cpart) {
  const int b  = blockIdx.x >> 5;
  const int tc = blockIdx.x & 31;
  const int t0 = tc << 6;
  __shared__ float a_sh[64];
  if (threadIdx.x < 64) a_sh[threadIdx.x] = a_ws[b * Tt + t0 + threadIdx.x];
  __syncthreads();
  f32x4 acc = {0.f, 0.f, 0.f, 0.f};
  const float* hb = h + ((size_t)b * Tt + t0) * Dd + threadIdx.x * 4;
#pragma unroll 4
  for (int t = 0; t < 64; ++t) {
    const f32x4 hv = *(const f32x4*)(hb + (size_t)t * Dd);
    acc += a_sh[t] * hv;
  }
  *(f32x4*)(cpart + ((size_t)(tc * 32 + b) << 10) + threadIdx.x * 4) = acc;
}

// ---------------- kernel 5b: reduce partials, store f32 ----------------
__global__ __launch_bounds__(256) void k_c2(const float* __restrict__ cpart,
                                            float* __restrict__ out) {
  const int gid = blockIdx.x * 256 + threadIdx.x;   // 0..32767
  const int b = gid >> 10;
  const int d = gid & 1023;
  float sv = 0.f;
#pragma unroll
  for (int tc = 0; tc < 32; ++tc) sv += cpart[((size_t)(tc * 32 + b) << 10) + d];
  out[gid] = sv;
}

extern "C" void kernel_launch(void* const* d_in, const int* in_sizes, int n_in,
                              void* d_out, int out_size, void* d_ws, size_t ws_size,
                              hipStream_t stream) {
  (void)in_sizes; (void)n_in; (void)out_size; (void)ws_size;
  const float* s  = (const float*)d_in[0];
  const float* h  = (const float*)d_in[1];
  const float* W  = (const float*)d_in[2];
  const float* U  = (const float*)d_in[3];
  const float* v  = (const float*)d_in[4];
  uint8_t* ws = (uint8_t*)d_ws;
  float*   w2_ws = (float*)ws;
  float*   e_ws  = (float*)(ws + WS_E);
  float*   a_ws  = (float*)(ws + WS_A);
  float*   cpart = (float*)(ws + WS_CP);
  uint8_t* U_ts  = ws + WS_UT;

  k_ws<<<128, 256, 0, stream>>>(s, W, w2_ws);
  k_ut<<<256, 256, 0, stream>>>(U, U_ts);
  k_e <<<1024, 256, 0, stream>>>(h, U_ts, w2_ws, v, e_ws);
  k_sm<<<Bb, 256, 0, stream>>>(e_ws, a_ws);
  k_c1<<<1024, 256, 0, stream>>>(h, a_ws, cpart);
  k_c2<<<128, 256, 0, stream>>>(cpart, (float*)d_out);
}